// Round 1
// baseline (4226.601 us; speedup 1.0000x reference)
//
#include <hip/hip_runtime.h>
#include <hip/hip_bf16.h>

#define Vn 10000
#define En 300
#define Hn 256
#define Gn 1024   // 4*H
#define Ln 9
#define Bn 128
#define Tn 512

static __device__ __forceinline__ float bf2f(unsigned short u) {
    return __uint_as_float(((unsigned int)u) << 16);
}
static __device__ __forceinline__ unsigned short f2bf(float f) {
    unsigned int x = __float_as_uint(f);
    return (unsigned short)((x + 0x7FFFu + ((x >> 16) & 1u)) >> 16);
}
static __device__ __forceinline__ float sigm(float x) {
    return 1.f / (1.f + __expf(-x));
}
static __device__ __forceinline__ float tanh_fast(float x) {
    return 2.f / (1.f + __expf(-2.f * x)) - 1.f;
}

// ---- transpose Wih (1024,300) -> WihT (300,1024), f32 ----
__global__ __launch_bounds__(256) void k_transpose_wih(
    const float* __restrict__ Wf, const float* __restrict__ Wb,
    float* __restrict__ Tf, float* __restrict__ Tb) {
    int n = blockIdx.x * 256 + threadIdx.x;          // < 307200
    const float* src = blockIdx.y ? Wb : Wf;
    float* dst = blockIdx.y ? Tb : Tf;
    int e = n / Gn, j = n % Gn;
    dst[n] = src[j * En + e];
}

// ---- pack Whh (1024,256) -> Wpk (128 k-pairs x 256 j) of uint4 bf16 ----
// uint4 holds gates {i,f,g,o} for (row j, col 2k2) and (row j, col 2k2+1)
__global__ __launch_bounds__(256) void k_pack_whh(
    const float* __restrict__ Wf, const float* __restrict__ Wb,
    uint4* __restrict__ Pf, uint4* __restrict__ Pb) {
    int n = blockIdx.x * 256 + threadIdx.x;          // < 32768
    const float* W = blockIdx.y ? Wb : Wf;
    uint4* O = blockIdx.y ? Pb : Pf;
    int k2 = n >> 8, j = n & 255;
    float2 a = *(const float2*)&W[(size_t)(j      ) * Hn + 2 * k2];
    float2 b = *(const float2*)&W[(size_t)(j + 256) * Hn + 2 * k2];
    float2 g = *(const float2*)&W[(size_t)(j + 512) * Hn + 2 * k2];
    float2 o = *(const float2*)&W[(size_t)(j + 768) * Hn + 2 * k2];
    uint4 r;
    r.x = (unsigned)f2bf(a.x) | ((unsigned)f2bf(b.x) << 16);
    r.y = (unsigned)f2bf(g.x) | ((unsigned)f2bf(o.x) << 16);
    r.z = (unsigned)f2bf(a.y) | ((unsigned)f2bf(b.y) << 16);
    r.w = (unsigned)f2bf(g.y) | ((unsigned)f2bf(o.y) << 16);
    O[n] = r;
}

// ---- P = emb @ WihT + b : (10000, 1024) bf16 per direction ----
__global__ __launch_bounds__(1024) void k_proj(
    const float* __restrict__ emb,
    const float* __restrict__ WihT_f, const float* __restrict__ WihT_b,
    const float* __restrict__ b_f, const float* __restrict__ b_b,
    unsigned short* __restrict__ Pf, unsigned short* __restrict__ Pb) {
    int tid = threadIdx.x;
    int tx = tid & 63, ty = tid >> 6;
    int dir = blockIdx.z;
    const float* WT = dir ? WihT_b : WihT_f;
    const float* bias = dir ? b_b : b_f;
    unsigned short* P = dir ? Pb : Pf;
    int v = blockIdx.x * 16 + ty;                    // 625*16 = 10000 exact
    int j0 = blockIdx.y * 256 + tx * 4;
    const float* arow = emb + (size_t)v * En;
    float4 acc = make_float4(0.f, 0.f, 0.f, 0.f);
    #pragma unroll 4
    for (int e = 0; e < En; ++e) {
        float a = arow[e];
        float4 w = *(const float4*)&WT[(size_t)e * Gn + j0];
        acc.x += a * w.x; acc.y += a * w.y; acc.z += a * w.z; acc.w += a * w.w;
    }
    float4 bb = *(const float4*)&bias[j0];
    acc.x += bb.x; acc.y += bb.y; acc.z += bb.z; acc.w += bb.w;
    ushort4 r;
    r.x = f2bf(acc.x); r.y = f2bf(acc.y); r.z = f2bf(acc.z); r.w = f2bf(acc.w);
    *(ushort4*)&P[(size_t)v * Gn + j0] = r;
}

// ---- persistent BiLSTM recurrence: 256 WGs = 2 dir x 128 batch ----
__global__ __launch_bounds__(256) void k_lstm(
    const int* __restrict__ ids,
    const uint4* __restrict__ Wpk_f, const uint4* __restrict__ Wpk_b,
    const unsigned short* __restrict__ Pf, const unsigned short* __restrict__ Pb,
    unsigned short* __restrict__ hs_f, unsigned short* __restrict__ hs_b) {
    __shared__ __align__(16) float h_lds[Hn];
    __shared__ int ids_lds[Tn];
    int j = threadIdx.x;
    int bid = blockIdx.x;
    int dir = bid >> 7;
    int batch = bid & 127;
    const uint4* Wp = (dir ? Wpk_b : Wpk_f) + j;
    const unsigned short* P = dir ? Pb : Pf;
    unsigned short* hs = dir ? hs_b : hs_f;
    ids_lds[j] = ids[batch * Tn + j];
    ids_lds[j + 256] = ids[batch * Tn + 256 + j];
    h_lds[j] = 0.f;
    float c = 0.f;
    __syncthreads();
    for (int s = 0; s < Tn; ++s) {
        int t = dir ? (Tn - 1 - s) : s;
        int id = ids_lds[t];
        const unsigned short* prow = P + (size_t)id * Gn;
        float ai = bf2f(prow[j]);
        float af = bf2f(prow[j + 256]);
        float ag = bf2f(prow[j + 512]);
        float ao = bf2f(prow[j + 768]);
        #pragma unroll 8
        for (int k2 = 0; k2 < Hn / 2; ++k2) {
            uint4 w = Wp[(size_t)k2 * 256];
            float2 hp = *(const float2*)&h_lds[2 * k2];
            ai += hp.x * __uint_as_float(w.x << 16);
            af += hp.x * __uint_as_float(w.x & 0xFFFF0000u);
            ag += hp.x * __uint_as_float(w.y << 16);
            ao += hp.x * __uint_as_float(w.y & 0xFFFF0000u);
            ai += hp.y * __uint_as_float(w.z << 16);
            af += hp.y * __uint_as_float(w.z & 0xFFFF0000u);
            ag += hp.y * __uint_as_float(w.w << 16);
            ao += hp.y * __uint_as_float(w.w & 0xFFFF0000u);
        }
        float cn = sigm(af) * c + sigm(ai) * tanh_fast(ag);
        float hn = sigm(ao) * tanh_fast(cn);
        c = cn;
        __syncthreads();             // all h reads of this step done
        h_lds[j] = hn;
        hs[(size_t)(t * Bn + batch) * Hn + j] = f2bf(hn);
        __syncthreads();             // new h visible
    }
}

// ---- emissions: em[t,b,l] = [hf|hb] . Wc[l] + bc[l], one wave per token ----
__global__ __launch_bounds__(256) void k_emit(
    const unsigned short* __restrict__ hs_f, const unsigned short* __restrict__ hs_b,
    const float* __restrict__ Wc, const float* __restrict__ bc,
    float* __restrict__ em) {
    __shared__ float wc_s[Ln * 2 * Hn];
    int tid = threadIdx.x;
    for (int i = tid; i < Ln * 2 * Hn; i += 256) wc_s[i] = Wc[i];
    __syncthreads();
    int lane = tid & 63, wid = tid >> 6;
    int tb = blockIdx.x * 4 + wid;                   // t*128 + b, < 65536
    const unsigned short* hf = hs_f + (size_t)tb * Hn;
    const unsigned short* hb = hs_b + (size_t)tb * Hn;
    uint2 uf = *(const uint2*)&hf[lane * 4];
    uint2 ub = *(const uint2*)&hb[lane * 4];
    float f0 = __uint_as_float(uf.x << 16), f1 = __uint_as_float(uf.x & 0xFFFF0000u);
    float f2v = __uint_as_float(uf.y << 16), f3 = __uint_as_float(uf.y & 0xFFFF0000u);
    float b0 = __uint_as_float(ub.x << 16), b1 = __uint_as_float(ub.x & 0xFFFF0000u);
    float b2 = __uint_as_float(ub.y << 16), b3 = __uint_as_float(ub.y & 0xFFFF0000u);
    #pragma unroll
    for (int l = 0; l < Ln; ++l) {
        const float* w = &wc_s[l * 2 * Hn];
        float p = f0 * w[4 * lane] + f1 * w[4 * lane + 1]
                + f2v * w[4 * lane + 2] + f3 * w[4 * lane + 3]
                + b0 * w[Hn + 4 * lane] + b1 * w[Hn + 4 * lane + 1]
                + b2 * w[Hn + 4 * lane + 2] + b3 * w[Hn + 4 * lane + 3];
        #pragma unroll
        for (int m = 32; m >= 1; m >>= 1) p += __shfl_xor(p, m, 64);
        if (lane == 0) em[(size_t)tb * Ln + l] = p + bc[l];
    }
}

// ---- CRF denominator: one 64-thread WG per batch, 9-state forward scan ----
__global__ __launch_bounds__(64) void k_crf_den(
    const float* __restrict__ em, const int* __restrict__ mask,
    const float* __restrict__ trans, const float* __restrict__ start,
    const float* __restrict__ endt, float* __restrict__ logZ) {
    int b = blockIdx.x, j = threadIdx.x;
    __shared__ float as[Ln];
    float tr[Ln];
    if (j < Ln) {
        #pragma unroll
        for (int i = 0; i < Ln; ++i) tr[i] = trans[i * Ln + j];
    }
    float alpha = 0.f;
    if (j < Ln) alpha = start[j] + em[(size_t)b * Ln + j];
    float e_cur = (j < Ln) ? em[(size_t)(Bn + b) * Ln + j] : 0.f;
    for (int t = 1; t < Tn; ++t) {
        if (j < Ln) as[j] = alpha;
        float e_nxt = 0.f;
        if (t + 1 < Tn && j < Ln) e_nxt = em[(size_t)((t + 1) * Bn + b) * Ln + j];
        int mt = mask[b * Tn + t];
        __syncthreads();
        if (j < Ln) {
            float m = -1e30f;
            #pragma unroll
            for (int i = 0; i < Ln; ++i) m = fmaxf(m, as[i] + tr[i]);
            float ssum = 0.f;
            #pragma unroll
            for (int i = 0; i < Ln; ++i) ssum += __expf(as[i] + tr[i] - m);
            float nxt = m + __logf(ssum) + e_cur;
            if (mt) alpha = nxt;
        }
        e_cur = e_nxt;
        __syncthreads();
    }
    if (j < Ln) as[j] = alpha + endt[j];
    __syncthreads();
    if (j == 0) {
        float m = -1e30f;
        for (int i = 0; i < Ln; ++i) m = fmaxf(m, as[i]);
        float ssum = 0.f;
        for (int i = 0; i < Ln; ++i) ssum += __expf(as[i] - m);
        logZ[b] = m + __logf(ssum);
    }
}

// ---- CRF numerator: gold-path score is a plain sum -> fully parallel over t ----
__global__ __launch_bounds__(64) void k_crf_num(
    const float* __restrict__ em, const int* __restrict__ labels,
    const int* __restrict__ mask, const float* __restrict__ trans,
    const float* __restrict__ start, const float* __restrict__ endt,
    float* __restrict__ score) {
    int b = blockIdx.x, lane = threadIdx.x;
    float acc = 0.f; int cnt = 0;
    for (int t = lane; t < Tn; t += 64) {
        int tag = labels[b * Tn + t];
        int mt = mask[b * Tn + t];
        cnt += mt;
        float e = em[(size_t)(t * Bn + b) * Ln + tag];
        if (t == 0) {
            acc += start[tag] + e;
        } else {
            int prev = labels[b * Tn + t - 1];
            if (mt) acc += trans[prev * Ln + tag] + e;
        }
    }
    #pragma unroll
    for (int m = 32; m >= 1; m >>= 1) {
        acc += __shfl_xor(acc, m, 64);
        cnt += __shfl_xor(cnt, m, 64);
    }
    if (lane == 0) {
        int send = cnt - 1;
        int last = labels[b * Tn + send];
        score[b] = acc + endt[last];
    }
}

__global__ __launch_bounds__(128) void k_final(
    const float* __restrict__ score, const float* __restrict__ logZ,
    float* __restrict__ out) {
    __shared__ float s_s[128];
    int tid = threadIdx.x;
    s_s[tid] = score[tid] - logZ[tid];
    #pragma unroll
    for (int m = 64; m >= 1; m >>= 1) {
        __syncthreads();
        if (tid < m) s_s[tid] += s_s[tid + m];
    }
    if (tid == 0) out[0] = -s_s[0] / (float)Bn;
}

extern "C" void kernel_launch(void* const* d_in, const int* in_sizes, int n_in,
                              void* d_out, int out_size, void* d_ws, size_t ws_size,
                              hipStream_t stream) {
    const int* ids = (const int*)d_in[0];
    const int* msk = (const int*)d_in[1];
    const int* lbl = (const int*)d_in[2];
    const float* emb = (const float*)d_in[3];
    const float* Wih_f = (const float*)d_in[4];
    const float* Whh_f = (const float*)d_in[5];
    const float* b_f = (const float*)d_in[6];
    const float* Wih_b = (const float*)d_in[7];
    const float* Whh_b = (const float*)d_in[8];
    const float* b_b = (const float*)d_in[9];
    const float* Wc = (const float*)d_in[10];
    const float* bc = (const float*)d_in[11];
    const float* trans = (const float*)d_in[12];
    const float* st = (const float*)d_in[13];
    const float* en = (const float*)d_in[14];

    char* ws = (char*)d_ws;
    float* WihT_f = (float*)ws;                 ws += (size_t)En * Gn * 4;      // 1,228,800
    float* WihT_b = (float*)ws;                 ws += (size_t)En * Gn * 4;
    uint4* Wpk_f = (uint4*)ws;                  ws += (size_t)128 * 256 * 16;   // 524,288
    uint4* Wpk_b = (uint4*)ws;                  ws += (size_t)128 * 256 * 16;
    unsigned short* Pf = (unsigned short*)ws;   ws += (size_t)Vn * Gn * 2;      // 20,480,000
    unsigned short* Pb = (unsigned short*)ws;   ws += (size_t)Vn * Gn * 2;
    unsigned short* hs_f = (unsigned short*)ws; ws += (size_t)Tn * Bn * Hn * 2; // 33,554,432
    unsigned short* hs_b = (unsigned short*)ws; ws += (size_t)Tn * Bn * Hn * 2;
    float* em = (float*)ws;                     ws += (size_t)Tn * Bn * Ln * 4; // 2,359,296
    float* score = (float*)ws;                  ws += 512;
    float* logZ = (float*)ws;                   ws += 512;

    k_transpose_wih<<<dim3(1200, 2), 256, 0, stream>>>(Wih_f, Wih_b, WihT_f, WihT_b);
    k_pack_whh<<<dim3(128, 2), 256, 0, stream>>>(Whh_f, Whh_b, Wpk_f, Wpk_b);
    k_proj<<<dim3(625, 4, 2), 1024, 0, stream>>>(emb, WihT_f, WihT_b, b_f, b_b, Pf, Pb);
    k_lstm<<<256, 256, 0, stream>>>(ids, Wpk_f, Wpk_b, Pf, Pb, hs_f, hs_b);
    k_emit<<<16384, 256, 0, stream>>>(hs_f, hs_b, Wc, bc, em);
    k_crf_den<<<128, 64, 0, stream>>>(em, msk, trans, st, en, logZ);
    k_crf_num<<<128, 64, 0, stream>>>(em, lbl, msk, trans, st, en, score);
    k_final<<<1, 128, 0, stream>>>(score, logZ, (float*)d_out);
}

// Round 2
// 3259.577 us; speedup vs baseline: 1.2967x; 1.2967x over previous
//
#include <hip/hip_runtime.h>
#include <hip/hip_bf16.h>

#define Vn 10000
#define En 300
#define Hn 256
#define Gn 1024   // 4*H
#define Ln 9
#define Bn 128
#define Tn 512

typedef float vf2 __attribute__((ext_vector_type(2)));

static __device__ __forceinline__ float bf2f(unsigned short u) {
    return __uint_as_float(((unsigned int)u) << 16);
}
static __device__ __forceinline__ unsigned short f2bf(float f) {
    unsigned int x = __float_as_uint(f);
    return (unsigned short)((x + 0x7FFFu + ((x >> 16) & 1u)) >> 16);
}
static __device__ __forceinline__ float sigm(float x) {
    return 1.f / (1.f + __expf(-x));
}
static __device__ __forceinline__ float tanh_fast(float x) {
    return 2.f / (1.f + __expf(-2.f * x)) - 1.f;
}

// ---- transpose Wih (1024,300) -> WihT (300,1024), f32 ----
__global__ __launch_bounds__(256) void k_transpose_wih(
    const float* __restrict__ Wf, const float* __restrict__ Wb,
    float* __restrict__ Tf, float* __restrict__ Tb) {
    int n = blockIdx.x * 256 + threadIdx.x;          // < 307200
    const float* src = blockIdx.y ? Wb : Wf;
    float* dst = blockIdx.y ? Tb : Tf;
    int e = n / Gn, j = n % Gn;
    dst[n] = src[j * En + e];
}

// ---- pack Whh (1024,256) f32 -> fp8 e4m3 tiles: Wpk[k4][j] uint4 ----
// uint4 = {gate i, gate f, gate g, gate o} dwords; each dword = 4 fp8 for
// k = 4*k4 .. 4*k4+3 of output row j. Encoded with the HW converter so the
// decode (v_cvt_pk_f32_fp8) is exactly inverse-consistent.
__global__ __launch_bounds__(256) void k_pack_whh(
    const float* __restrict__ Wf, const float* __restrict__ Wb,
    uint4* __restrict__ Pf, uint4* __restrict__ Pb) {
    int n = blockIdx.x * 256 + threadIdx.x;          // < 16384
    const float* W = blockIdx.y ? Wb : Wf;
    uint4* O = blockIdx.y ? Pb : Pf;
    int k4 = n >> 8, j = n & 255;
    unsigned int d[4];
    #pragma unroll
    for (int g = 0; g < 4; ++g) {
        float4 w = *(const float4*)&W[(size_t)(g * 256 + j) * Hn + 4 * k4];
        int v = 0;
        v = __builtin_amdgcn_cvt_pk_fp8_f32(w.x, w.y, v, false);
        v = __builtin_amdgcn_cvt_pk_fp8_f32(w.z, w.w, v, true);
        d[g] = (unsigned int)v;
    }
    uint4 r; r.x = d[0]; r.y = d[1]; r.z = d[2]; r.w = d[3];
    O[n] = r;
}

// ---- P = emb @ WihT + b : (10000, 1024) bf16 per direction ----
__global__ __launch_bounds__(1024) void k_proj(
    const float* __restrict__ emb,
    const float* __restrict__ WihT_f, const float* __restrict__ WihT_b,
    const float* __restrict__ b_f, const float* __restrict__ b_b,
    unsigned short* __restrict__ Pf, unsigned short* __restrict__ Pb) {
    int tid = threadIdx.x;
    int tx = tid & 63, ty = tid >> 6;
    int dir = blockIdx.z;
    const float* WT = dir ? WihT_b : WihT_f;
    const float* bias = dir ? b_b : b_f;
    unsigned short* P = dir ? Pb : Pf;
    int v = blockIdx.x * 16 + ty;                    // 625*16 = 10000 exact
    int j0 = blockIdx.y * 256 + tx * 4;
    const float* arow = emb + (size_t)v * En;
    float4 acc = make_float4(0.f, 0.f, 0.f, 0.f);
    #pragma unroll 4
    for (int e = 0; e < En; ++e) {
        float a = arow[e];
        float4 w = *(const float4*)&WT[(size_t)e * Gn + j0];
        acc.x += a * w.x; acc.y += a * w.y; acc.z += a * w.z; acc.w += a * w.w;
    }
    float4 bb = *(const float4*)&bias[j0];
    acc.x += bb.x; acc.y += bb.y; acc.z += bb.z; acc.w += bb.w;
    ushort4 r;
    r.x = f2bf(acc.x); r.y = f2bf(acc.y); r.z = f2bf(acc.z); r.w = f2bf(acc.w);
    *(ushort4*)&P[(size_t)v * Gn + j0] = r;
}

// ---- persistent BiLSTM recurrence: 256 WGs = 2 dir x 128 batch ----
// fp8 Whh stream (256 KB/WG/step from L2), h double-buffered in LDS
// (1 barrier/step), P-row gather software-pipelined one step ahead.
__global__ __launch_bounds__(256) void k_lstm(
    const int* __restrict__ ids,
    const uint4* __restrict__ Wpk_f, const uint4* __restrict__ Wpk_b,
    const unsigned short* __restrict__ Pf, const unsigned short* __restrict__ Pb,
    unsigned short* __restrict__ hs_f, unsigned short* __restrict__ hs_b) {
    __shared__ __align__(16) float hbuf[2][Hn];
    __shared__ int ids_lds[Tn];
    int j = threadIdx.x;
    int bid = blockIdx.x;
    int dir = bid >> 7;
    int batch = bid & 127;
    const uint4* Wp = (dir ? Wpk_b : Wpk_f) + j;
    const unsigned short* P = dir ? Pb : Pf;
    unsigned short* hs = dir ? hs_b : hs_f;
    ids_lds[j] = ids[batch * Tn + j];
    ids_lds[j + 256] = ids[batch * Tn + 256 + j];
    hbuf[0][j] = 0.f;
    float c = 0.f;
    __syncthreads();

    int t0 = dir ? (Tn - 1) : 0;
    {   // prime the P pipeline
        const unsigned short* prow = P + (size_t)ids_lds[t0] * Gn;
        unsigned short u0 = prow[j], u1 = prow[j + 256], u2 = prow[j + 512], u3 = prow[j + 768];
        float pi = bf2f(u0), pf = bf2f(u1), pg = bf2f(u2), po = bf2f(u3);

        for (int s = 0; s < Tn; ++s) {
            int cur = s & 1, nxt = cur ^ 1;
            int t = dir ? (Tn - 1 - s) : s;
            // issue next step's P loads now; waited on at end of step
            int s2 = s + 1; if (s2 >= Tn) s2 = Tn - 1;
            int t2 = dir ? (Tn - 1 - s2) : s2;
            const unsigned short* prow2 = P + (size_t)ids_lds[t2] * Gn;
            unsigned short n0 = prow2[j], n1 = prow2[j + 256];
            unsigned short n2 = prow2[j + 512], n3 = prow2[j + 768];

            vf2 aI = {pi, 0.f}, aF = {pf, 0.f}, aG = {pg, 0.f}, aO = {po, 0.f};
            const float4* h4p = (const float4*)&hbuf[cur][0];
            #pragma unroll 8
            for (int k4 = 0; k4 < 64; ++k4) {
                uint4 w = Wp[(size_t)k4 * 256];
                float4 h4 = h4p[k4];
                vf2 hA = {h4.x, h4.y}, hB = {h4.z, h4.w};
                aI += hA * __builtin_amdgcn_cvt_pk_f32_fp8((int)w.x, false);
                aI += hB * __builtin_amdgcn_cvt_pk_f32_fp8((int)w.x, true);
                aF += hA * __builtin_amdgcn_cvt_pk_f32_fp8((int)w.y, false);
                aF += hB * __builtin_amdgcn_cvt_pk_f32_fp8((int)w.y, true);
                aG += hA * __builtin_amdgcn_cvt_pk_f32_fp8((int)w.z, false);
                aG += hB * __builtin_amdgcn_cvt_pk_f32_fp8((int)w.z, true);
                aO += hA * __builtin_amdgcn_cvt_pk_f32_fp8((int)w.w, false);
                aO += hB * __builtin_amdgcn_cvt_pk_f32_fp8((int)w.w, true);
            }
            float gi = aI.x + aI.y, gf = aF.x + aF.y;
            float gg = aG.x + aG.y, go = aO.x + aO.y;
            float cn = sigm(gf) * c + sigm(gi) * tanh_fast(gg);
            float hn = sigm(go) * tanh_fast(cn);
            c = cn;
            hbuf[nxt][j] = hn;                                  // other buffer: no race
            hs[(size_t)(t * Bn + batch) * Hn + j] = f2bf(hn);
            __syncthreads();                                    // new h visible
            pi = bf2f(n0); pf = bf2f(n1); pg = bf2f(n2); po = bf2f(n3);
        }
    }
}

// ---- emissions: em[t,b,l] = [hf|hb] . Wc[l] + bc[l], one wave per token ----
__global__ __launch_bounds__(256) void k_emit(
    const unsigned short* __restrict__ hs_f, const unsigned short* __restrict__ hs_b,
    const float* __restrict__ Wc, const float* __restrict__ bc,
    float* __restrict__ em) {
    __shared__ float wc_s[Ln * 2 * Hn];
    int tid = threadIdx.x;
    for (int i = tid; i < Ln * 2 * Hn; i += 256) wc_s[i] = Wc[i];
    __syncthreads();
    int lane = tid & 63, wid = tid >> 6;
    int tb = blockIdx.x * 4 + wid;                   // t*128 + b, < 65536
    const unsigned short* hf = hs_f + (size_t)tb * Hn;
    const unsigned short* hb = hs_b + (size_t)tb * Hn;
    uint2 uf = *(const uint2*)&hf[lane * 4];
    uint2 ub = *(const uint2*)&hb[lane * 4];
    float f0 = __uint_as_float(uf.x << 16), f1 = __uint_as_float(uf.x & 0xFFFF0000u);
    float f2v = __uint_as_float(uf.y << 16), f3 = __uint_as_float(uf.y & 0xFFFF0000u);
    float b0 = __uint_as_float(ub.x << 16), b1 = __uint_as_float(ub.x & 0xFFFF0000u);
    float b2 = __uint_as_float(ub.y << 16), b3 = __uint_as_float(ub.y & 0xFFFF0000u);
    #pragma unroll
    for (int l = 0; l < Ln; ++l) {
        const float* w = &wc_s[l * 2 * Hn];
        float p = f0 * w[4 * lane] + f1 * w[4 * lane + 1]
                + f2v * w[4 * lane + 2] + f3 * w[4 * lane + 3]
                + b0 * w[Hn + 4 * lane] + b1 * w[Hn + 4 * lane + 1]
                + b2 * w[Hn + 4 * lane + 2] + b3 * w[Hn + 4 * lane + 3];
        #pragma unroll
        for (int m = 32; m >= 1; m >>= 1) p += __shfl_xor(p, m, 64);
        if (lane == 0) em[(size_t)tb * Ln + l] = p + bc[l];
    }
}

// ---- CRF denominator: one 64-thread WG per batch, 9-state forward scan ----
__global__ __launch_bounds__(64) void k_crf_den(
    const float* __restrict__ em, const int* __restrict__ mask,
    const float* __restrict__ trans, const float* __restrict__ start,
    const float* __restrict__ endt, float* __restrict__ logZ) {
    int b = blockIdx.x, j = threadIdx.x;
    __shared__ float as[Ln];
    float tr[Ln];
    if (j < Ln) {
        #pragma unroll
        for (int i = 0; i < Ln; ++i) tr[i] = trans[i * Ln + j];
    }
    float alpha = 0.f;
    if (j < Ln) alpha = start[j] + em[(size_t)b * Ln + j];
    float e_cur = (j < Ln) ? em[(size_t)(Bn + b) * Ln + j] : 0.f;
    for (int t = 1; t < Tn; ++t) {
        if (j < Ln) as[j] = alpha;
        float e_nxt = 0.f;
        if (t + 1 < Tn && j < Ln) e_nxt = em[(size_t)((t + 1) * Bn + b) * Ln + j];
        int mt = mask[b * Tn + t];
        __syncthreads();
        if (j < Ln) {
            float m = -1e30f;
            #pragma unroll
            for (int i = 0; i < Ln; ++i) m = fmaxf(m, as[i] + tr[i]);
            float ssum = 0.f;
            #pragma unroll
            for (int i = 0; i < Ln; ++i) ssum += __expf(as[i] + tr[i] - m);
            float nxt = m + __logf(ssum) + e_cur;
            if (mt) alpha = nxt;
        }
        e_cur = e_nxt;
        __syncthreads();
    }
    if (j < Ln) as[j] = alpha + endt[j];
    __syncthreads();
    if (j == 0) {
        float m = -1e30f;
        for (int i = 0; i < Ln; ++i) m = fmaxf(m, as[i]);
        float ssum = 0.f;
        for (int i = 0; i < Ln; ++i) ssum += __expf(as[i] - m);
        logZ[b] = m + __logf(ssum);
    }
}

// ---- CRF numerator: gold-path score is a plain sum -> fully parallel over t ----
__global__ __launch_bounds__(64) void k_crf_num(
    const float* __restrict__ em, const int* __restrict__ labels,
    const int* __restrict__ mask, const float* __restrict__ trans,
    const float* __restrict__ start, const float* __restrict__ endt,
    float* __restrict__ score) {
    int b = blockIdx.x, lane = threadIdx.x;
    float acc = 0.f; int cnt = 0;
    for (int t = lane; t < Tn; t += 64) {
        int tag = labels[b * Tn + t];
        int mt = mask[b * Tn + t];
        cnt += mt;
        float e = em[(size_t)(t * Bn + b) * Ln + tag];
        if (t == 0) {
            acc += start[tag] + e;
        } else {
            int prev = labels[b * Tn + t - 1];
            if (mt) acc += trans[prev * Ln + tag] + e;
        }
    }
    #pragma unroll
    for (int m = 32; m >= 1; m >>= 1) {
        acc += __shfl_xor(acc, m, 64);
        cnt += __shfl_xor(cnt, m, 64);
    }
    if (lane == 0) {
        int send = cnt - 1;
        int last = labels[b * Tn + send];
        score[b] = acc + endt[last];
    }
}

__global__ __launch_bounds__(128) void k_final(
    const float* __restrict__ score, const float* __restrict__ logZ,
    float* __restrict__ out) {
    __shared__ float s_s[128];
    int tid = threadIdx.x;
    s_s[tid] = score[tid] - logZ[tid];
    #pragma unroll
    for (int m = 64; m >= 1; m >>= 1) {
        __syncthreads();
        if (tid < m) s_s[tid] += s_s[tid + m];
    }
    if (tid == 0) out[0] = -s_s[0] / (float)Bn;
}

extern "C" void kernel_launch(void* const* d_in, const int* in_sizes, int n_in,
                              void* d_out, int out_size, void* d_ws, size_t ws_size,
                              hipStream_t stream) {
    const int* ids = (const int*)d_in[0];
    const int* msk = (const int*)d_in[1];
    const int* lbl = (const int*)d_in[2];
    const float* emb = (const float*)d_in[3];
    const float* Wih_f = (const float*)d_in[4];
    const float* Whh_f = (const float*)d_in[5];
    const float* b_f = (const float*)d_in[6];
    const float* Wih_b = (const float*)d_in[7];
    const float* Whh_b = (const float*)d_in[8];
    const float* b_b = (const float*)d_in[9];
    const float* Wc = (const float*)d_in[10];
    const float* bc = (const float*)d_in[11];
    const float* trans = (const float*)d_in[12];
    const float* st = (const float*)d_in[13];
    const float* en = (const float*)d_in[14];

    char* ws = (char*)d_ws;
    float* WihT_f = (float*)ws;                 ws += (size_t)En * Gn * 4;      // 1,228,800
    float* WihT_b = (float*)ws;                 ws += (size_t)En * Gn * 4;
    uint4* Wpk_f = (uint4*)ws;                  ws += (size_t)64 * 256 * 16;    // 262,144 (fp8)
    uint4* Wpk_b = (uint4*)ws;                  ws += (size_t)64 * 256 * 16;
    unsigned short* Pf = (unsigned short*)ws;   ws += (size_t)Vn * Gn * 2;      // 20,480,000
    unsigned short* Pb = (unsigned short*)ws;   ws += (size_t)Vn * Gn * 2;
    unsigned short* hs_f = (unsigned short*)ws; ws += (size_t)Tn * Bn * Hn * 2; // 33,554,432
    unsigned short* hs_b = (unsigned short*)ws; ws += (size_t)Tn * Bn * Hn * 2;
    float* em = (float*)ws;                     ws += (size_t)Tn * Bn * Ln * 4; // 2,359,296
    float* score = (float*)ws;                  ws += 512;
    float* logZ = (float*)ws;                   ws += 512;

    k_transpose_wih<<<dim3(1200, 2), 256, 0, stream>>>(Wih_f, Wih_b, WihT_f, WihT_b);
    k_pack_whh<<<dim3(64, 2), 256, 0, stream>>>(Whh_f, Whh_b, Wpk_f, Wpk_b);
    k_proj<<<dim3(625, 4, 2), 1024, 0, stream>>>(emb, WihT_f, WihT_b, b_f, b_b, Pf, Pb);
    k_lstm<<<256, 256, 0, stream>>>(ids, Wpk_f, Wpk_b, Pf, Pb, hs_f, hs_b);
    k_emit<<<16384, 256, 0, stream>>>(hs_f, hs_b, Wc, bc, em);
    k_crf_den<<<128, 64, 0, stream>>>(em, msk, trans, st, en, logZ);
    k_crf_num<<<128, 64, 0, stream>>>(em, lbl, msk, trans, st, en, score);
    k_final<<<1, 128, 0, stream>>>(score, logZ, (float*)d_out);
}

// Round 3
// 2081.333 us; speedup vs baseline: 2.0307x; 1.5661x over previous
//
#include <hip/hip_runtime.h>
#include <hip/hip_bf16.h>

#define Vn 10000
#define En 300
#define Hn 256
#define Gn 1024   // 4*H
#define Ln 9
#define Bn 128
#define Tn 512

static __device__ __forceinline__ float bf2f(unsigned short u) {
    return __uint_as_float(((unsigned int)u) << 16);
}
static __device__ __forceinline__ unsigned short f2bf(float f) {
    unsigned int x = __float_as_uint(f);
    return (unsigned short)((x + 0x7FFFu + ((x >> 16) & 1u)) >> 16);
}
static __device__ __forceinline__ float sigm(float x) {
    return 1.f / (1.f + __expf(-x));
}
static __device__ __forceinline__ float tanh_fast(float x) {
    return 2.f / (1.f + __expf(-2.f * x)) - 1.f;
}
static __device__ __forceinline__ int dot4(unsigned int w, unsigned int h, int acc) {
    return __builtin_amdgcn_sdot4((int)w, (int)h, acc, false);
}

// ---- transpose Wih (1024,300) -> WihT (300,1024), f32 ----
__global__ __launch_bounds__(256) void k_transpose_wih(
    const float* __restrict__ Wf, const float* __restrict__ Wb,
    float* __restrict__ Tf, float* __restrict__ Tb) {
    int n = blockIdx.x * 256 + threadIdx.x;          // < 307200
    const float* src = blockIdx.y ? Wb : Wf;
    float* dst = blockIdx.y ? Tb : Tf;
    int e = n / Gn, j = n % Gn;
    dst[n] = src[j * En + e];
}

// ---- quantize Whh (1024,256) f32 -> i8 with per-gate-row scale ----
// Output layout per half (rows [0,512) -> qA, rows [512,1024) -> qB):
//   uint dword d of local row rl at flat uint index ((d>>2)*512 + rl)*4 + (d&3)
//   i.e. uint4 tiles [d4][512]; dword d packs k = 4d..4d+3.
// scl[j] = rowmax / (127*127): gate = scl[j] * sdot + P.
__global__ __launch_bounds__(64) void k_quant_whh(
    const float* __restrict__ Wf, const float* __restrict__ Wb,
    unsigned int* __restrict__ qA_f, unsigned int* __restrict__ qB_f,
    unsigned int* __restrict__ qA_b, unsigned int* __restrict__ qB_b,
    float* __restrict__ scl_f, float* __restrict__ scl_b) {
    int j = blockIdx.x;                 // 0..1023 (gate-row)
    int dir = blockIdx.y;
    int lane = threadIdx.x;             // 0..63
    const float* W = dir ? Wb : Wf;
    float4 w = *(const float4*)&W[(size_t)j * Hn + 4 * lane];
    float m = fmaxf(fmaxf(fabsf(w.x), fabsf(w.y)), fmaxf(fabsf(w.z), fabsf(w.w)));
    #pragma unroll
    for (int sft = 32; sft >= 1; sft >>= 1) m = fmaxf(m, __shfl_xor(m, sft, 64));
    float inv = (m > 0.f) ? (127.f / m) : 0.f;
    int q0 = (int)rintf(w.x * inv), q1 = (int)rintf(w.y * inv);
    int q2 = (int)rintf(w.z * inv), q3 = (int)rintf(w.w * inv);
    unsigned int d = (q0 & 255) | ((q1 & 255) << 8) | ((q2 & 255) << 16) | ((q3 & 255) << 24);
    unsigned int* dst;
    int rl;
    if (j < 512) { dst = dir ? qA_b : qA_f; rl = j; }
    else         { dst = dir ? qB_b : qB_f; rl = j - 512; }
    int d4 = lane >> 2, sub = lane & 3;
    dst[(size_t)(d4 * 512 + rl) * 4 + sub] = d;
    if (lane == 0) (dir ? scl_b : scl_f)[j] = m / 16129.f;
}

// ---- P = emb @ WihT + b : (10000, 1024) bf16 per direction ----
__global__ __launch_bounds__(1024) void k_proj(
    const float* __restrict__ emb,
    const float* __restrict__ WihT_f, const float* __restrict__ WihT_b,
    const float* __restrict__ b_f, const float* __restrict__ b_b,
    unsigned short* __restrict__ Pf, unsigned short* __restrict__ Pb) {
    int tid = threadIdx.x;
    int tx = tid & 63, ty = tid >> 6;
    int dir = blockIdx.z;
    const float* WT = dir ? WihT_b : WihT_f;
    const float* bias = dir ? b_b : b_f;
    unsigned short* P = dir ? Pb : Pf;
    int v = blockIdx.x * 16 + ty;                    // 625*16 = 10000 exact
    int j0 = blockIdx.y * 256 + tx * 4;
    const float* arow = emb + (size_t)v * En;
    float4 acc = make_float4(0.f, 0.f, 0.f, 0.f);
    #pragma unroll 4
    for (int e = 0; e < En; ++e) {
        float a = arow[e];
        float4 w = *(const float4*)&WT[(size_t)e * Gn + j0];
        acc.x += a * w.x; acc.y += a * w.y; acc.z += a * w.z; acc.w += a * w.w;
    }
    float4 bb = *(const float4*)&bias[j0];
    acc.x += bb.x; acc.y += bb.y; acc.z += bb.z; acc.w += bb.w;
    ushort4 r;
    r.x = f2bf(acc.x); r.y = f2bf(acc.y); r.z = f2bf(acc.z); r.w = f2bf(acc.w);
    *(ushort4*)&P[(size_t)v * Gn + j0] = r;
}

// ---- persistent BiLSTM recurrence: 128 WGs = 2 dir x 64 batch-pairs ----
// i8 weights: gates i,f (rows 0..511) LDS-resident; gates g,o (rows 512..1023)
// streamed from L2 each step. 512 threads: thread owns gate-rows {tid, tid+512}
// for BOTH batches of its pair (weight dword loaded once, used twice).
// h kept as i8 (scale 127) in LDS, read via wave-uniform broadcast.
__global__ __launch_bounds__(512) void k_lstm(
    const int* __restrict__ ids,
    const uint4* __restrict__ qA_f, const uint4* __restrict__ qB_f,
    const uint4* __restrict__ qA_b, const uint4* __restrict__ qB_b,
    const float* __restrict__ scl_f, const float* __restrict__ scl_b,
    const unsigned short* __restrict__ Pf, const unsigned short* __restrict__ Pb,
    unsigned short* __restrict__ hs_f, unsigned short* __restrict__ hs_b) {
    __shared__ uint4 wlds[16 * 512];       // 128 KB: resident rows [0,512)
    __shared__ float g_stage[2][1024];     // 8 KB: gate preacts per batch
    __shared__ uint4 h8v[2][16];           // 512 B: h as i8, dword d = units 4d..4d+3
    __shared__ int ids_lds[2][Tn];         // 4 KB
    int tid = threadIdx.x;
    int dir = blockIdx.y;
    int bpair = blockIdx.x;
    int b0 = 2 * bpair;
    const uint4* qA = dir ? qA_b : qA_f;
    const uint4* qB = dir ? qB_b : qB_f;
    const float* scl = dir ? scl_b : scl_f;
    const unsigned short* P = dir ? Pb : Pf;
    unsigned short* hs = dir ? hs_b : hs_f;

    #pragma unroll
    for (int i = 0; i < 16; ++i) wlds[i * 512 + tid] = qA[i * 512 + tid];
    ids_lds[0][tid] = ids[(size_t)b0 * Tn + tid];
    ids_lds[1][tid] = ids[(size_t)(b0 + 1) * Tn + tid];
    if (tid < 128) ((unsigned int*)h8v)[tid] = 0u;
    float sA = scl[tid], sB = scl[tid + 512];
    float c = 0.f;                         // cell state for (bb, u) role below
    int bb = tid >> 8, u = tid & 255;
    __syncthreads();

    for (int s = 0; s < Tn; ++s) {
        int t = dir ? (Tn - 1 - s) : s;
        int id0 = ids_lds[0][t], id1 = ids_lds[1][t];
        // P-row gather: issued now, consumed after the dot loop (~700 cyc later)
        unsigned short rA0 = P[(size_t)id0 * Gn + tid];
        unsigned short rA1 = P[(size_t)id1 * Gn + tid];
        unsigned short rB0 = P[(size_t)id0 * Gn + tid + 512];
        unsigned short rB1 = P[(size_t)id1 * Gn + tid + 512];

        // prefetch this step's streamed weight rows (gates g,o)
        uint4 wsr[16];
        #pragma unroll
        for (int i = 0; i < 16; ++i) wsr[i] = qB[i * 512 + tid];

        int accA0 = 0, accA1 = 0, accB0 = 0, accB1 = 0;
        #pragma unroll
        for (int d4 = 0; d4 < 16; ++d4) {
            uint4 wA = wlds[d4 * 512 + tid];
            uint4 h0 = h8v[0][d4];
            uint4 h1 = h8v[1][d4];
            accA0 = dot4(wA.x, h0.x, accA0); accA0 = dot4(wA.y, h0.y, accA0);
            accA0 = dot4(wA.z, h0.z, accA0); accA0 = dot4(wA.w, h0.w, accA0);
            accA1 = dot4(wA.x, h1.x, accA1); accA1 = dot4(wA.y, h1.y, accA1);
            accA1 = dot4(wA.z, h1.z, accA1); accA1 = dot4(wA.w, h1.w, accA1);
            uint4 wB = wsr[d4];
            accB0 = dot4(wB.x, h0.x, accB0); accB0 = dot4(wB.y, h0.y, accB0);
            accB0 = dot4(wB.z, h0.z, accB0); accB0 = dot4(wB.w, h0.w, accB0);
            accB1 = dot4(wB.x, h1.x, accB1); accB1 = dot4(wB.y, h1.y, accB1);
            accB1 = dot4(wB.z, h1.z, accB1); accB1 = dot4(wB.w, h1.w, accB1);
        }
        g_stage[0][tid]       = sA * (float)accA0 + bf2f(rA0);
        g_stage[1][tid]       = sA * (float)accA1 + bf2f(rA1);
        g_stage[0][tid + 512] = sB * (float)accB0 + bf2f(rB0);
        g_stage[1][tid + 512] = sB * (float)accB1 + bf2f(rB1);
        __syncthreads();
        // epilogue: thread handles (batch bb, unit u); 512 = 2 x 256 exactly
        float gi = g_stage[bb][u];
        float gf = g_stage[bb][u + 256];
        float gg = g_stage[bb][u + 512];
        float go = g_stage[bb][u + 768];
        float cn = sigm(gf) * c + sigm(gi) * tanh_fast(gg);
        float hn = sigm(go) * tanh_fast(cn);
        c = cn;
        hs[(size_t)(t * Bn + b0 + bb) * Hn + u] = f2bf(hn);
        ((char*)h8v)[bb * 256 + u] = (char)(int)rintf(127.f * hn);
        __syncthreads();
    }
}

// ---- emissions: em[t,b,l] = [hf|hb] . Wc[l] + bc[l], one wave per token ----
__global__ __launch_bounds__(256) void k_emit(
    const unsigned short* __restrict__ hs_f, const unsigned short* __restrict__ hs_b,
    const float* __restrict__ Wc, const float* __restrict__ bc,
    float* __restrict__ em) {
    __shared__ float wc_s[Ln * 2 * Hn];
    int tid = threadIdx.x;
    for (int i = tid; i < Ln * 2 * Hn; i += 256) wc_s[i] = Wc[i];
    __syncthreads();
    int lane = tid & 63, wid = tid >> 6;
    int tb = blockIdx.x * 4 + wid;                   // t*128 + b, < 65536
    const unsigned short* hf = hs_f + (size_t)tb * Hn;
    const unsigned short* hb = hs_b + (size_t)tb * Hn;
    uint2 uf = *(const uint2*)&hf[lane * 4];
    uint2 ub = *(const uint2*)&hb[lane * 4];
    float f0 = __uint_as_float(uf.x << 16), f1 = __uint_as_float(uf.x & 0xFFFF0000u);
    float f2v = __uint_as_float(uf.y << 16), f3 = __uint_as_float(uf.y & 0xFFFF0000u);
    float b0 = __uint_as_float(ub.x << 16), b1 = __uint_as_float(ub.x & 0xFFFF0000u);
    float b2 = __uint_as_float(ub.y << 16), b3 = __uint_as_float(ub.y & 0xFFFF0000u);
    #pragma unroll
    for (int l = 0; l < Ln; ++l) {
        const float* w = &wc_s[l * 2 * Hn];
        float p = f0 * w[4 * lane] + f1 * w[4 * lane + 1]
                + f2v * w[4 * lane + 2] + f3 * w[4 * lane + 3]
                + b0 * w[Hn + 4 * lane] + b1 * w[Hn + 4 * lane + 1]
                + b2 * w[Hn + 4 * lane + 2] + b3 * w[Hn + 4 * lane + 3];
        #pragma unroll
        for (int m = 32; m >= 1; m >>= 1) p += __shfl_xor(p, m, 64);
        if (lane == 0) em[(size_t)tb * Ln + l] = p + bc[l];
    }
}

// ---- CRF denominator: one 64-thread WG per batch, 9-state forward scan ----
__global__ __launch_bounds__(64) void k_crf_den(
    const float* __restrict__ em, const int* __restrict__ mask,
    const float* __restrict__ trans, const float* __restrict__ start,
    const float* __restrict__ endt, float* __restrict__ logZ) {
    int b = blockIdx.x, j = threadIdx.x;
    __shared__ float as[Ln];
    float tr[Ln];
    if (j < Ln) {
        #pragma unroll
        for (int i = 0; i < Ln; ++i) tr[i] = trans[i * Ln + j];
    }
    float alpha = 0.f;
    if (j < Ln) alpha = start[j] + em[(size_t)b * Ln + j];
    float e_cur = (j < Ln) ? em[(size_t)(Bn + b) * Ln + j] : 0.f;
    for (int t = 1; t < Tn; ++t) {
        if (j < Ln) as[j] = alpha;
        float e_nxt = 0.f;
        if (t + 1 < Tn && j < Ln) e_nxt = em[(size_t)((t + 1) * Bn + b) * Ln + j];
        int mt = mask[b * Tn + t];
        __syncthreads();
        if (j < Ln) {
            float m = -1e30f;
            #pragma unroll
            for (int i = 0; i < Ln; ++i) m = fmaxf(m, as[i] + tr[i]);
            float ssum = 0.f;
            #pragma unroll
            for (int i = 0; i < Ln; ++i) ssum += __expf(as[i] + tr[i] - m);
            float nxt = m + __logf(ssum) + e_cur;
            if (mt) alpha = nxt;
        }
        e_cur = e_nxt;
        __syncthreads();
    }
    if (j < Ln) as[j] = alpha + endt[j];
    __syncthreads();
    if (j == 0) {
        float m = -1e30f;
        for (int i = 0; i < Ln; ++i) m = fmaxf(m, as[i]);
        float ssum = 0.f;
        for (int i = 0; i < Ln; ++i) ssum += __expf(as[i] - m);
        logZ[b] = m + __logf(ssum);
    }
}

// ---- CRF numerator: gold-path score is a plain sum -> fully parallel over t ----
__global__ __launch_bounds__(64) void k_crf_num(
    const float* __restrict__ em, const int* __restrict__ labels,
    const int* __restrict__ mask, const float* __restrict__ trans,
    const float* __restrict__ start, const float* __restrict__ endt,
    float* __restrict__ score) {
    int b = blockIdx.x, lane = threadIdx.x;
    float acc = 0.f; int cnt = 0;
    for (int t = lane; t < Tn; t += 64) {
        int tag = labels[b * Tn + t];
        int mt = mask[b * Tn + t];
        cnt += mt;
        float e = em[(size_t)(t * Bn + b) * Ln + tag];
        if (t == 0) {
            acc += start[tag] + e;
        } else {
            int prev = labels[b * Tn + t - 1];
            if (mt) acc += trans[prev * Ln + tag] + e;
        }
    }
    #pragma unroll
    for (int m = 32; m >= 1; m >>= 1) {
        acc += __shfl_xor(acc, m, 64);
        cnt += __shfl_xor(cnt, m, 64);
    }
    if (lane == 0) {
        int send = cnt - 1;
        int last = labels[b * Tn + send];
        score[b] = acc + endt[last];
    }
}

__global__ __launch_bounds__(128) void k_final(
    const float* __restrict__ score, const float* __restrict__ logZ,
    float* __restrict__ out) {
    __shared__ float s_s[128];
    int tid = threadIdx.x;
    s_s[tid] = score[tid] - logZ[tid];
    #pragma unroll
    for (int m = 64; m >= 1; m >>= 1) {
        __syncthreads();
        if (tid < m) s_s[tid] += s_s[tid + m];
    }
    if (tid == 0) out[0] = -s_s[0] / (float)Bn;
}

extern "C" void kernel_launch(void* const* d_in, const int* in_sizes, int n_in,
                              void* d_out, int out_size, void* d_ws, size_t ws_size,
                              hipStream_t stream) {
    const int* ids = (const int*)d_in[0];
    const int* msk = (const int*)d_in[1];
    const int* lbl = (const int*)d_in[2];
    const float* emb = (const float*)d_in[3];
    const float* Wih_f = (const float*)d_in[4];
    const float* Whh_f = (const float*)d_in[5];
    const float* b_f = (const float*)d_in[6];
    const float* Wih_b = (const float*)d_in[7];
    const float* Whh_b = (const float*)d_in[8];
    const float* b_b = (const float*)d_in[9];
    const float* Wc = (const float*)d_in[10];
    const float* bc = (const float*)d_in[11];
    const float* trans = (const float*)d_in[12];
    const float* st = (const float*)d_in[13];
    const float* en = (const float*)d_in[14];

    char* ws = (char*)d_ws;
    float* WihT_f = (float*)ws;                 ws += (size_t)En * Gn * 4;      // 1,228,800
    float* WihT_b = (float*)ws;                 ws += (size_t)En * Gn * 4;
    unsigned int* qA_f = (unsigned int*)ws;     ws += 131072;                   // 128 KB each
    unsigned int* qB_f = (unsigned int*)ws;     ws += 131072;
    unsigned int* qA_b = (unsigned int*)ws;     ws += 131072;
    unsigned int* qB_b = (unsigned int*)ws;     ws += 131072;
    float* scl_f = (float*)ws;                  ws += 4096;
    float* scl_b = (float*)ws;                  ws += 4096;
    unsigned short* Pf = (unsigned short*)ws;   ws += (size_t)Vn * Gn * 2;      // 20,480,000
    unsigned short* Pb = (unsigned short*)ws;   ws += (size_t)Vn * Gn * 2;
    unsigned short* hs_f = (unsigned short*)ws; ws += (size_t)Tn * Bn * Hn * 2; // 33,554,432
    unsigned short* hs_b = (unsigned short*)ws; ws += (size_t)Tn * Bn * Hn * 2;
    float* em = (float*)ws;                     ws += (size_t)Tn * Bn * Ln * 4; // 2,359,296
    float* score = (float*)ws;                  ws += 512;
    float* logZ = (float*)ws;                   ws += 512;

    k_transpose_wih<<<dim3(1200, 2), 256, 0, stream>>>(Wih_f, Wih_b, WihT_f, WihT_b);
    k_quant_whh<<<dim3(1024, 2), 64, 0, stream>>>(Whh_f, Whh_b, qA_f, qB_f, qA_b, qB_b, scl_f, scl_b);
    k_proj<<<dim3(625, 4, 2), 1024, 0, stream>>>(emb, WihT_f, WihT_b, b_f, b_b, Pf, Pb);
    k_lstm<<<dim3(64, 2), 512, 0, stream>>>(ids,
        (const uint4*)qA_f, (const uint4*)qB_f, (const uint4*)qA_b, (const uint4*)qB_b,
        scl_f, scl_b, Pf, Pb, hs_f, hs_b);
    k_emit<<<16384, 256, 0, stream>>>(hs_f, hs_b, Wc, bc, em);
    k_crf_den<<<128, 64, 0, stream>>>(em, msk, trans, st, en, logZ);
    k_crf_num<<<128, 64, 0, stream>>>(em, lbl, msk, trans, st, en, score);
    k_final<<<1, 128, 0, stream>>>(score, logZ, (float*)d_out);
}

// Round 4
// 1304.759 us; speedup vs baseline: 3.2394x; 1.5952x over previous
//
#include <hip/hip_runtime.h>
#include <hip/hip_bf16.h>

#define Vn 10000
#define En 300
#define Hn 256
#define Gn 1024   // 4*H
#define Ln 9
#define Bn 128
#define Tn 512

static __device__ __forceinline__ float bf2f(unsigned short u) {
    return __uint_as_float(((unsigned int)u) << 16);
}
static __device__ __forceinline__ unsigned short f2bf(float f) {
    unsigned int x = __float_as_uint(f);
    return (unsigned short)((x + 0x7FFFu + ((x >> 16) & 1u)) >> 16);
}
static __device__ __forceinline__ float sigm(float x) {
    return 1.f / (1.f + __expf(-x));
}
static __device__ __forceinline__ float tanh_fast(float x) {
    return 2.f / (1.f + __expf(-2.f * x)) - 1.f;
}
static __device__ __forceinline__ int dot4(unsigned int w, unsigned int h, int acc) {
    return __builtin_amdgcn_sdot4((int)w, (int)h, acc, false);
}

// ---- transpose Wih (1024,300) -> WihT (300,1024), f32 ----
__global__ __launch_bounds__(256) void k_transpose_wih(
    const float* __restrict__ Wf, const float* __restrict__ Wb,
    float* __restrict__ Tf, float* __restrict__ Tb) {
    int n = blockIdx.x * 256 + threadIdx.x;          // < 307200
    const float* src = blockIdx.y ? Wb : Wf;
    float* dst = blockIdx.y ? Tb : Tf;
    int e = n / Gn, j = n % Gn;
    dst[n] = src[j * En + e];
}

// ---- quantize Whh (1024,256) f32 -> i8, per-gate-row scale ----
// Layout: dword d (k=4d..4d+3) of row j at uint index ((d>>2)*1024 + j)*4 + (d&3)
// i.e. uint4 tiles [d4][1024] -> k_lstm thread j reads q[d4*1024 + j] coalesced.
__global__ __launch_bounds__(64) void k_quant_whh(
    const float* __restrict__ Wf, const float* __restrict__ Wb,
    unsigned int* __restrict__ q_f, unsigned int* __restrict__ q_b,
    float* __restrict__ scl_f, float* __restrict__ scl_b) {
    int j = blockIdx.x;                 // 0..1023 (gate-row)
    int dir = blockIdx.y;
    int lane = threadIdx.x;             // 0..63 = dword index d
    const float* W = dir ? Wb : Wf;
    unsigned int* dst = dir ? q_b : q_f;
    float4 w = *(const float4*)&W[(size_t)j * Hn + 4 * lane];
    float m = fmaxf(fmaxf(fabsf(w.x), fabsf(w.y)), fmaxf(fabsf(w.z), fabsf(w.w)));
    #pragma unroll
    for (int sft = 32; sft >= 1; sft >>= 1) m = fmaxf(m, __shfl_xor(m, sft, 64));
    float inv = (m > 0.f) ? (127.f / m) : 0.f;
    int q0 = (int)rintf(w.x * inv), q1 = (int)rintf(w.y * inv);
    int q2 = (int)rintf(w.z * inv), q3 = (int)rintf(w.w * inv);
    unsigned int d = (q0 & 255) | ((q1 & 255) << 8) | ((q2 & 255) << 16) | ((q3 & 255) << 24);
    dst[(size_t)((lane >> 2) * 1024 + j) * 4 + (lane & 3)] = d;
    if (lane == 0) (dir ? scl_b : scl_f)[j] = m / 16129.f;
}

// ---- P = emb @ WihT + b : (10000, 1024) bf16 per direction ----
// 256 thr: tx=tid&63 -> 4 j-cols, ty=tid>>6 -> 4 v-rows each (16 v per block).
// WT float4 loaded once per (e,j) per wave (4x L1 redundancy vs 16x before).
__global__ __launch_bounds__(256) void k_proj(
    const float* __restrict__ emb,
    const float* __restrict__ WihT_f, const float* __restrict__ WihT_b,
    const float* __restrict__ b_f, const float* __restrict__ b_b,
    unsigned short* __restrict__ Pf, unsigned short* __restrict__ Pb) {
    int tid = threadIdx.x;
    int tx = tid & 63, ty = tid >> 6;
    int dir = blockIdx.z;
    const float* WT = dir ? WihT_b : WihT_f;
    const float* bias = dir ? b_b : b_f;
    unsigned short* P = dir ? Pb : Pf;
    int v0 = blockIdx.x * 16 + ty * 4;               // 625*16 = 10000 exact
    int j0 = blockIdx.y * 256 + tx * 4;
    float4 acc0 = {0,0,0,0}, acc1 = {0,0,0,0}, acc2 = {0,0,0,0}, acc3 = {0,0,0,0};
    for (int e0 = 0; e0 < En; e0 += 4) {             // 300 = 75*4 exact
        float4 a0 = *(const float4*)&emb[(size_t)(v0 + 0) * En + e0];
        float4 a1 = *(const float4*)&emb[(size_t)(v0 + 1) * En + e0];
        float4 a2 = *(const float4*)&emb[(size_t)(v0 + 2) * En + e0];
        float4 a3 = *(const float4*)&emb[(size_t)(v0 + 3) * En + e0];
        float4 w0 = *(const float4*)&WT[(size_t)(e0 + 0) * Gn + j0];
        float4 w1 = *(const float4*)&WT[(size_t)(e0 + 1) * Gn + j0];
        float4 w2 = *(const float4*)&WT[(size_t)(e0 + 2) * Gn + j0];
        float4 w3 = *(const float4*)&WT[(size_t)(e0 + 3) * Gn + j0];
        acc0.x += a0.x*w0.x + a0.y*w1.x + a0.z*w2.x + a0.w*w3.x;
        acc0.y += a0.x*w0.y + a0.y*w1.y + a0.z*w2.y + a0.w*w3.y;
        acc0.z += a0.x*w0.z + a0.y*w1.z + a0.z*w2.z + a0.w*w3.z;
        acc0.w += a0.x*w0.w + a0.y*w1.w + a0.z*w2.w + a0.w*w3.w;
        acc1.x += a1.x*w0.x + a1.y*w1.x + a1.z*w2.x + a1.w*w3.x;
        acc1.y += a1.x*w0.y + a1.y*w1.y + a1.z*w2.y + a1.w*w3.y;
        acc1.z += a1.x*w0.z + a1.y*w1.z + a1.z*w2.z + a1.w*w3.z;
        acc1.w += a1.x*w0.w + a1.y*w1.w + a1.z*w2.w + a1.w*w3.w;
        acc2.x += a2.x*w0.x + a2.y*w1.x + a2.z*w2.x + a2.w*w3.x;
        acc2.y += a2.x*w0.y + a2.y*w1.y + a2.z*w2.y + a2.w*w3.y;
        acc2.z += a2.x*w0.z + a2.y*w1.z + a2.z*w2.z + a2.w*w3.z;
        acc2.w += a2.x*w0.w + a2.y*w1.w + a2.z*w2.w + a2.w*w3.w;
        acc3.x += a3.x*w0.x + a3.y*w1.x + a3.z*w2.x + a3.w*w3.x;
        acc3.y += a3.x*w0.y + a3.y*w1.y + a3.z*w2.y + a3.w*w3.y;
        acc3.z += a3.x*w0.z + a3.y*w1.z + a3.z*w2.z + a3.w*w3.z;
        acc3.w += a3.x*w0.w + a3.y*w1.w + a3.z*w2.w + a3.w*w3.w;
    }
    float4 bb = *(const float4*)&bias[j0];
    float4 av[4] = {acc0, acc1, acc2, acc3};
    #pragma unroll
    for (int r = 0; r < 4; ++r) {
        ushort4 o;
        o.x = f2bf(av[r].x + bb.x); o.y = f2bf(av[r].y + bb.y);
        o.z = f2bf(av[r].z + bb.z); o.w = f2bf(av[r].w + bb.w);
        *(ushort4*)&P[(size_t)(v0 + r) * Gn + j0] = o;
    }
}

// ---- persistent BiLSTM recurrence: 256 WGs = 2 dir x 128 batch, 1024 thr ----
// Whole i8 Whh lives in REGISTERS: thread j holds gate-row j (16 uint4).
// K-loop = 64 sdot4 + 16 broadcast LDS reads of h; no weight traffic.
// Emissions fused: waves 7..15 compute the 9-label partial dots from f32 h.
__global__ __launch_bounds__(1024, 4) void k_lstm(
    const int* __restrict__ ids,
    const uint4* __restrict__ q_f, const uint4* __restrict__ q_b,
    const float* __restrict__ scl_f, const float* __restrict__ scl_b,
    const unsigned short* __restrict__ Pf, const unsigned short* __restrict__ Pb,
    const float* __restrict__ Wc,
    float* __restrict__ em_pf, float* __restrict__ em_pb) {
    __shared__ float g_stage[Gn];            // 4 KB gate preacts
    __shared__ float hstage[Hn];             // 1 KB f32 h for emission dot
    __shared__ uint4 h8v[Hn / 16];           // 256 B i8 h for sdot4
    __shared__ int ids_lds[Tn];              // 2 KB
    __shared__ float wc_lds[Ln][Hn];         // 9 KB this dir's half of Wc
    int tid = threadIdx.x;
    int dir = blockIdx.x >> 7;
    int batch = blockIdx.x & 127;
    const uint4* q = dir ? q_b : q_f;
    const unsigned short* P = dir ? Pb : Pf;
    float* em_p = dir ? em_pb : em_pf;

    uint4 w[16];
    #pragma unroll
    for (int d4 = 0; d4 < 16; ++d4) w[d4] = q[(size_t)d4 * 1024 + tid];
    float sc = (dir ? scl_b : scl_f)[tid];
    if (tid < Tn) ids_lds[tid] = ids[batch * Tn + tid];
    for (int i = tid; i < Ln * Hn; i += 1024)
        wc_lds[i >> 8][i & 255] = Wc[(size_t)(i >> 8) * 512 + dir * 256 + (i & 255)];
    if (tid < 16) { uint4 z = {0, 0, 0, 0}; h8v[tid] = z; }
    float c = 0.f;
    __syncthreads();

    int t0 = dir ? (Tn - 1) : 0;
    float pcur = bf2f(P[(size_t)ids_lds[t0] * Gn + tid]);

    for (int s = 0; s < Tn; ++s) {
        int t = dir ? (Tn - 1 - s) : s;
        int s2 = (s + 1 < Tn) ? s + 1 : Tn - 1;
        int t2 = dir ? (Tn - 1 - s2) : s2;
        unsigned short pnx = P[(size_t)ids_lds[t2] * Gn + tid];  // next-step prefetch

        int acc = 0;
        #pragma unroll
        for (int d4 = 0; d4 < 16; ++d4) {
            uint4 h4 = h8v[d4];                       // broadcast read
            acc = dot4(w[d4].x, h4.x, acc);
            acc = dot4(w[d4].y, h4.y, acc);
            acc = dot4(w[d4].z, h4.z, acc);
            acc = dot4(w[d4].w, h4.w, acc);
        }
        g_stage[tid] = sc * (float)acc + pcur;
        __syncthreads();                              // B1: gates ready
        if (tid < Hn) {
            float gi = g_stage[tid];
            float gf = g_stage[tid + 256];
            float gg = g_stage[tid + 512];
            float go = g_stage[tid + 768];
            float cn = sigm(gf) * c + sigm(gi) * tanh_fast(gg);
            float hn = sigm(go) * tanh_fast(cn);
            c = cn;
            hstage[tid] = hn;
            ((char*)h8v)[tid] = (char)(int)rintf(127.f * hn);
        }
        __syncthreads();                              // B2: new h visible
        if (tid >= 448) {                             // waves 7..15: emission partial
            int l = (tid >> 6) - 7;                   // 0..8
            int lane = tid & 63;
            float4 h4 = *(const float4*)&hstage[lane * 4];
            float4 w4 = *(const float4*)&wc_lds[l][lane * 4];
            float p = h4.x * w4.x + h4.y * w4.y + h4.z * w4.z + h4.w * w4.w;
            #pragma unroll
            for (int m = 32; m >= 1; m >>= 1) p += __shfl_xor(p, m, 64);
            if (lane == 0) em_p[((size_t)t * Bn + batch) * Ln + l] = p;
        }
        pcur = bf2f(pnx);
    }
}

// ---- CRF denominator: one 64-thread WG per batch, 9-state forward scan ----
__global__ __launch_bounds__(64) void k_crf_den(
    const float* __restrict__ pf, const float* __restrict__ pb,
    const float* __restrict__ bc, const int* __restrict__ mask,
    const float* __restrict__ trans, const float* __restrict__ start,
    const float* __restrict__ endt, float* __restrict__ logZ) {
    int b = blockIdx.x, j = threadIdx.x;
    __shared__ float as[Ln];
    float tr[Ln];
    float bcj = 0.f;
    if (j < Ln) {
        #pragma unroll
        for (int i = 0; i < Ln; ++i) tr[i] = trans[i * Ln + j];
        bcj = bc[j];
    }
    float alpha = 0.f;
    if (j < Ln) {
        size_t i0 = (size_t)b * Ln + j;
        alpha = start[j] + pf[i0] + pb[i0] + bcj;
    }
    float e_cur = 0.f;
    if (j < Ln) {
        size_t i1 = (size_t)(Bn + b) * Ln + j;
        e_cur = pf[i1] + pb[i1] + bcj;
    }
    for (int t = 1; t < Tn; ++t) {
        if (j < Ln) as[j] = alpha;
        float e_nxt = 0.f;
        if (t + 1 < Tn && j < Ln) {
            size_t ix = (size_t)((t + 1) * Bn + b) * Ln + j;
            e_nxt = pf[ix] + pb[ix] + bcj;
        }
        int mt = mask[b * Tn + t];
        __syncthreads();
        if (j < Ln) {
            float m = -1e30f;
            #pragma unroll
            for (int i = 0; i < Ln; ++i) m = fmaxf(m, as[i] + tr[i]);
            float ssum = 0.f;
            #pragma unroll
            for (int i = 0; i < Ln; ++i) ssum += __expf(as[i] + tr[i] - m);
            float nxt = m + __logf(ssum) + e_cur;
            if (mt) alpha = nxt;
        }
        e_cur = e_nxt;
        __syncthreads();
    }
    if (j < Ln) as[j] = alpha + endt[j];
    __syncthreads();
    if (j == 0) {
        float m = -1e30f;
        for (int i = 0; i < Ln; ++i) m = fmaxf(m, as[i]);
        float ssum = 0.f;
        for (int i = 0; i < Ln; ++i) ssum += __expf(as[i] - m);
        logZ[b] = m + __logf(ssum);
    }
}

// ---- CRF numerator: gold-path score is a plain sum -> fully parallel over t ----
__global__ __launch_bounds__(64) void k_crf_num(
    const float* __restrict__ pf, const float* __restrict__ pb,
    const float* __restrict__ bc, const int* __restrict__ labels,
    const int* __restrict__ mask, const float* __restrict__ trans,
    const float* __restrict__ start, const float* __restrict__ endt,
    float* __restrict__ score) {
    int b = blockIdx.x, lane = threadIdx.x;
    float acc = 0.f; int cnt = 0;
    for (int t = lane; t < Tn; t += 64) {
        int tag = labels[b * Tn + t];
        int mt = mask[b * Tn + t];
        cnt += mt;
        size_t ix = (size_t)(t * Bn + b) * Ln + tag;
        float e = pf[ix] + pb[ix] + bc[tag];
        if (t == 0) {
            acc += start[tag] + e;
        } else {
            int prev = labels[b * Tn + t - 1];
            if (mt) acc += trans[prev * Ln + tag] + e;
        }
    }
    #pragma unroll
    for (int m = 32; m >= 1; m >>= 1) {
        acc += __shfl_xor(acc, m, 64);
        cnt += __shfl_xor(cnt, m, 64);
    }
    if (lane == 0) {
        int send = cnt - 1;
        int last = labels[b * Tn + send];
        score[b] = acc + endt[last];
    }
}

__global__ __launch_bounds__(128) void k_final(
    const float* __restrict__ score, const float* __restrict__ logZ,
    float* __restrict__ out) {
    __shared__ float s_s[128];
    int tid = threadIdx.x;
    s_s[tid] = score[tid] - logZ[tid];
    #pragma unroll
    for (int m = 64; m >= 1; m >>= 1) {
        __syncthreads();
        if (tid < m) s_s[tid] += s_s[tid + m];
    }
    if (tid == 0) out[0] = -s_s[0] / (float)Bn;
}

extern "C" void kernel_launch(void* const* d_in, const int* in_sizes, int n_in,
                              void* d_out, int out_size, void* d_ws, size_t ws_size,
                              hipStream_t stream) {
    const int* ids = (const int*)d_in[0];
    const int* msk = (const int*)d_in[1];
    const int* lbl = (const int*)d_in[2];
    const float* emb = (const float*)d_in[3];
    const float* Wih_f = (const float*)d_in[4];
    const float* Whh_f = (const float*)d_in[5];
    const float* b_f = (const float*)d_in[6];
    const float* Wih_b = (const float*)d_in[7];
    const float* Whh_b = (const float*)d_in[8];
    const float* b_b = (const float*)d_in[9];
    const float* Wc = (const float*)d_in[10];
    const float* bc = (const float*)d_in[11];
    const float* trans = (const float*)d_in[12];
    const float* st = (const float*)d_in[13];
    const float* en = (const float*)d_in[14];

    char* ws = (char*)d_ws;
    float* WihT_f = (float*)ws;                 ws += (size_t)En * Gn * 4;      // 1,228,800
    float* WihT_b = (float*)ws;                 ws += (size_t)En * Gn * 4;
    unsigned int* q_f = (unsigned int*)ws;      ws += 262144;                   // 256 KB
    unsigned int* q_b = (unsigned int*)ws;      ws += 262144;
    float* scl_f = (float*)ws;                  ws += 4096;
    float* scl_b = (float*)ws;                  ws += 4096;
    unsigned short* Pf = (unsigned short*)ws;   ws += (size_t)Vn * Gn * 2;      // 20,480,000
    unsigned short* Pb = (unsigned short*)ws;   ws += (size_t)Vn * Gn * 2;
    float* em_pf = (float*)ws;                  ws += (size_t)Tn * Bn * Ln * 4; // 2,359,296
    float* em_pb = (float*)ws;                  ws += (size_t)Tn * Bn * Ln * 4;
    float* score = (float*)ws;                  ws += 512;
    float* logZ = (float*)ws;                   ws += 512;

    k_transpose_wih<<<dim3(1200, 2), 256, 0, stream>>>(Wih_f, Wih_b, WihT_f, WihT_b);
    k_quant_whh<<<dim3(1024, 2), 64, 0, stream>>>(Whh_f, Whh_b, q_f, q_b, scl_f, scl_b);
    k_proj<<<dim3(625, 4, 2), 256, 0, stream>>>(emb, WihT_f, WihT_b, b_f, b_b, Pf, Pb);
    k_lstm<<<256, 1024, 0, stream>>>(ids, (const uint4*)q_f, (const uint4*)q_b,
                                     scl_f, scl_b, Pf, Pb, Wc, em_pf, em_pb);
    k_crf_den<<<128, 64, 0, stream>>>(em_pf, em_pb, bc, msk, trans, st, en, logZ);
    k_crf_num<<<128, 64, 0, stream>>>(em_pf, em_pb, bc, lbl, msk, trans, st, en, score);
    k_final<<<1, 128, 0, stream>>>(score, logZ, (float*)d_out);
}